// Round 1
// baseline (286.097 us; speedup 1.0000x reference)
//
#include <hip/hip_runtime.h>
#include <cstdint>
#include <cstddef>

#define B_    8
#define C_    256
#define DWH   13824      // 24*24*24
#define P3    27
#define JW    512        // HEADS*WORD
#define COUT_ 256

// ---- workspace layout (float offsets) ----
#define OFF_XMEAN 0               // B*C*27          = 55296
#define OFF_WQT   55296           // 27*512 (transposed) = 13824
#define OFF_WKT   69120           // 13824
#define OFF_BQ    82944           // 512
#define OFF_BK    83456           // 512
#define OFF_BETA  83968           // 256
#define OFF_QH    84224           // B*C*512 = 1048576
#define OFF_KH    1132800         // 1048576
#define OFF_A     2181376         // B*C*C = 524288
#define OFF_M     2705664         // B*256*256 = 524288
// total = 3229952 floats = 12.92 MB

// ============ K1: 3x3x3 block-mean pool: x (B,C,24,24,24) -> xmean (B,C,27) ============
__global__ __launch_bounds__(256) void k_pool(const float* __restrict__ x,
                                              float* __restrict__ xmean) {
    int bc = blockIdx.x;                       // b*C + c
    __shared__ float p0[576], p1[576], p2[576];
    const float* xb = x + (size_t)bc * DWH;
    for (int t = threadIdx.x; t < 576; t += 256) {
        int g  = t >> 6;                       // 0..8 : (pd,pw) group
        int s  = t & 63;
        int pd = g / 3, pw = g % 3;
        int d  = pd * 8 + (s >> 3);
        int w  = pw * 8 + (s & 7);
        const float4* r = (const float4*)(xb + ((size_t)d * 24 + w) * 24);
        float4 f0 = r[0], f1 = r[1], f2 = r[2], f3 = r[3], f4v = r[4], f5 = r[5];
        p0[t] = f0.x + f0.y + f0.z + f0.w + f1.x + f1.y + f1.z + f1.w;
        p1[t] = f2.x + f2.y + f2.z + f2.w + f3.x + f3.y + f3.z + f3.w;
        p2[t] = f4v.x + f4v.y + f4v.z + f4v.w + f5.x + f5.y + f5.z + f5.w;
    }
    __syncthreads();
    int tid = threadIdx.x;
    if (tid < 27) {
        int pd = tid / 9, pw = (tid / 3) % 3, ph = tid % 3;
        int g = pd * 3 + pw;
        const float* src = (ph == 0) ? p0 : (ph == 1 ? p1 : p2);
        float s = 0.f;
        #pragma unroll 8
        for (int i = 0; i < 64; ++i) s += src[g * 64 + i];
        xmean[(size_t)bc * P3 + tid] = s * (1.0f / 512.0f);
    }
}

// ============ K2: fold projection chains into combined 512x27 mats + biases + beta ============
__global__ __launch_bounds__(128) void k_combine(
    const float* __restrict__ qk_w, const float* __restrict__ qk_b,
    const float* __restrict__ wq_w, const float* __restrict__ wq_b,
    const float* __restrict__ wk_w, const float* __restrict__ wk_b,
    const float* __restrict__ fch_b, const float* __restrict__ conv_w,
    const float* __restrict__ conv_b,
    float* __restrict__ WqT, float* __restrict__ WkT,
    float* __restrict__ bq, float* __restrict__ bk, float* __restrict__ beta) {
    int t = blockIdx.x * 128 + threadIdx.x;
    if (t < 13824) {
        int j = t / 27, p = t % 27;
        float s = 0.f;
        for (int e = 0; e < 128; ++e) s += wq_w[j * 128 + e] * qk_w[e * 27 + p];
        WqT[p * 512 + j] = s;                  // transposed for coalesced reads
    } else if (t < 27648) {
        int u = t - 13824, j = u / 27, p = u % 27;
        float s = 0.f;
        for (int e = 0; e < 128; ++e) s += wk_w[j * 128 + e] * qk_w[(128 + e) * 27 + p];
        WkT[p * 512 + j] = s;
    } else if (t < 28160) {
        int j = t - 27648;
        float s = wq_b[j];
        for (int e = 0; e < 128; ++e) s += wq_w[j * 128 + e] * qk_b[e];
        bq[j] = s;
    } else if (t < 28672) {
        int j = t - 28160;
        float s = wk_b[j];
        for (int e = 0; e < 128; ++e) s += wk_w[j * 128 + e] * qk_b[128 + e];
        bk[j] = s;
    } else if (t < 28928) {
        int o = t - 28672;
        float s = 0.f;
        for (int c = 0; c < 256; ++c) s += conv_w[o * 256 + c];
        beta[o] = fch_b[0] * s + conv_b[o];
    }
}

// ============ K3: qh/kh = combined proj of xmean; qh pre-scaled by 1/sqrt(64) ============
__global__ __launch_bounds__(512) void k_qkh(
    const float* __restrict__ xmean, const float* __restrict__ WqT,
    const float* __restrict__ WkT, const float* __restrict__ bq,
    const float* __restrict__ bk, float* __restrict__ qh, float* __restrict__ kh) {
    int bc = blockIdx.y * C_ + blockIdx.x;
    __shared__ float xm[P3];
    if (threadIdx.x < P3) xm[threadIdx.x] = xmean[(size_t)bc * P3 + threadIdx.x];
    __syncthreads();
    int j = threadIdx.x;
    float q = bq[j], k = bk[j];
    #pragma unroll
    for (int p = 0; p < P3; ++p) {
        float xv = xm[p];
        q += WqT[p * 512 + j] * xv;
        k += WkT[p * 512 + j] * xv;
    }
    qh[(size_t)bc * JW + j] = q * 0.125f;      // 1/sqrt(WORD)
    kh[(size_t)bc * JW + j] = k;
}

// ============ K4: scores + softmax + head-combine -> A, attn_out ============
// block = (b, ctile of 8 rows); thread t owns key index k=t
__global__ __launch_bounds__(256) void k_attn(
    const float* __restrict__ qh, const float* __restrict__ kh,
    const float* __restrict__ fch_w, const float* __restrict__ fch_b,
    float* __restrict__ A, float* __restrict__ attn_out) {
    int b = blockIdx.y;
    int c0 = blockIdx.x * 8;
    int t = threadIdx.x;
    __shared__ float qs[8 * JW];               // 16 KB
    __shared__ float ss[8][256];               // 8 KB
    __shared__ float mx[8], den[8];
    {
        const float4* src = (const float4*)(qh + ((size_t)(b * C_ + c0)) * JW);
        float4* dst = (float4*)qs;
        #pragma unroll
        for (int i = 0; i < 4; ++i) dst[t + 256 * i] = src[t + 256 * i];
    }
    float areg[8];
    #pragma unroll
    for (int i = 0; i < 8; ++i) areg[i] = 0.f;
    __syncthreads();
    int lane = t & 63, wv = t >> 6;
    for (int h = 0; h < 8; ++h) {
        float khv[64];
        const float4* kp = (const float4*)(kh + ((size_t)(b * C_ + t)) * JW + h * 64);
        #pragma unroll
        for (int i = 0; i < 16; ++i) {
            float4 v = kp[i];
            khv[i * 4] = v.x; khv[i * 4 + 1] = v.y; khv[i * 4 + 2] = v.z; khv[i * 4 + 3] = v.w;
        }
        #pragma unroll
        for (int cl = 0; cl < 8; ++cl) {
            const float4* qrow = (const float4*)(qs + cl * JW + h * 64);
            float dot = 0.f;
            #pragma unroll
            for (int i = 0; i < 16; ++i) {
                float4 qv = qrow[i];
                dot += qv.x * khv[i * 4] + qv.y * khv[i * 4 + 1]
                     + qv.z * khv[i * 4 + 2] + qv.w * khv[i * 4 + 3];
            }
            ss[cl][t] = dot;
        }
        __syncthreads();
        // each wave reduces 2 rows (max, sum of exp) over 256 entries
        #pragma unroll
        for (int rr = 0; rr < 2; ++rr) {
            int cl = wv * 2 + rr;
            float4 v = *(const float4*)&ss[cl][lane * 4];
            float m = fmaxf(fmaxf(v.x, v.y), fmaxf(v.z, v.w));
            for (int off = 32; off; off >>= 1) m = fmaxf(m, __shfl_xor(m, off, 64));
            float s = expf(v.x - m) + expf(v.y - m) + expf(v.z - m) + expf(v.w - m);
            for (int off = 32; off; off >>= 1) s += __shfl_xor(s, off, 64);
            if (lane == 0) { mx[cl] = m; den[cl] = s; }
        }
        __syncthreads();
        float fw = fch_w[h];
        #pragma unroll
        for (int cl = 0; cl < 8; ++cl)
            areg[cl] += expf(ss[cl][t] - mx[cl]) * (fw / den[cl]);
        __syncthreads();                       // before next h reuses ss
    }
    float fb = fch_b[0];
    #pragma unroll
    for (int cl = 0; cl < 8; ++cl) {
        size_t idx = ((size_t)(b * C_ + c0 + cl)) * C_ + t;
        A[idx] = areg[cl];
        attn_out[idx] = areg[cl] + fb;
    }
}

// ============ K5: M[b] = conv_w @ A[b] + conv_w ============
__global__ __launch_bounds__(256) void k_M(
    const float* __restrict__ A, const float* __restrict__ conv_w,
    float* __restrict__ M) {
    int b = blockIdx.y;
    int o0 = blockIdx.x * 8;
    int t = threadIdx.x;
    __shared__ float cw[8][256];
    #pragma unroll
    for (int r = 0; r < 8; ++r) cw[r][t] = conv_w[(o0 + r) * 256 + t];
    __syncthreads();
    float acc[8] = {0.f, 0.f, 0.f, 0.f, 0.f, 0.f, 0.f, 0.f};
    const float* Ab = A + (size_t)b * C_ * C_;
    for (int c = 0; c < 256; ++c) {
        float av = Ab[(size_t)c * 256 + t];
        #pragma unroll
        for (int r = 0; r < 8; ++r) acc[r] += cw[r][c] * av;
    }
    #pragma unroll
    for (int r = 0; r < 8; ++r)
        M[((size_t)b * C_ + o0 + r) * C_ + t] = acc[r] + conv_w[(o0 + r) * 256 + t];
}

// ============ K6: out[b,o,n] = sum_k M[b,o,k]*x[b,k,n] + beta[o] ============
// block tile: 256(o) x 64(n); 256 threads, 8x8 per thread; K staged in chunks of 16
__global__ __launch_bounds__(256) void k_out(
    const float* __restrict__ M, const float* __restrict__ x,
    const float* __restrict__ beta, float* __restrict__ out) {
    int b = blockIdx.y;
    int n0 = blockIdx.x * 64;
    int t = threadIdx.x;
    int tx = t & 7, ty = t >> 3;               // tx: n-groups, ty: o-groups
    __shared__ float Ms[16][256];              // transposed M tile (k-major)
    __shared__ float Xs[16][64];
    float acc[8][8];
    #pragma unroll
    for (int i = 0; i < 8; ++i)
        #pragma unroll
        for (int j = 0; j < 8; ++j) acc[i][j] = 0.f;
    const float* Mb = M + (size_t)b * 256 * 256;
    const float* xb = x + (size_t)b * 256 * DWH;
    for (int k0 = 0; k0 < 256; k0 += 16) {
        const float4* mp = (const float4*)(Mb + (size_t)t * 256 + k0);
        #pragma unroll
        for (int q = 0; q < 4; ++q) {
            float4 v = mp[q];
            Ms[q * 4 + 0][t] = v.x; Ms[q * 4 + 1][t] = v.y;
            Ms[q * 4 + 2][t] = v.z; Ms[q * 4 + 3][t] = v.w;
        }
        int xr = t >> 4, xc = t & 15;
        float4 xv = *(const float4*)(xb + (size_t)(k0 + xr) * DWH + n0 + xc * 4);
        *(float4*)&Xs[xr][xc * 4] = xv;
        __syncthreads();
        #pragma unroll
        for (int kk = 0; kk < 16; ++kk) {
            float4 a0 = *(const float4*)&Ms[kk][ty * 4];
            float4 a1 = *(const float4*)&Ms[kk][128 + ty * 4];
            float4 b0 = *(const float4*)&Xs[kk][tx * 4];
            float4 b1 = *(const float4*)&Xs[kk][32 + tx * 4];
            float a[8] = {a0.x, a0.y, a0.z, a0.w, a1.x, a1.y, a1.z, a1.w};
            float bb[8] = {b0.x, b0.y, b0.z, b0.w, b1.x, b1.y, b1.z, b1.w};
            #pragma unroll
            for (int i = 0; i < 8; ++i)
                #pragma unroll
                for (int j = 0; j < 8; ++j)
                    acc[i][j] = fmaf(a[i], bb[j], acc[i][j]);
        }
        __syncthreads();
    }
    #pragma unroll
    for (int i = 0; i < 8; ++i) {
        int o = (i < 4) ? (ty * 4 + i) : (128 + ty * 4 + (i - 4));
        float bet = beta[o];
        float* orow = out + ((size_t)(b * 256 + o)) * DWH + n0;
        float4 v0 = {acc[i][0] + bet, acc[i][1] + bet, acc[i][2] + bet, acc[i][3] + bet};
        float4 v1 = {acc[i][4] + bet, acc[i][5] + bet, acc[i][6] + bet, acc[i][7] + bet};
        *(float4*)(orow + tx * 4) = v0;
        *(float4*)(orow + 32 + tx * 4) = v1;
    }
}

extern "C" void kernel_launch(void* const* d_in, const int* in_sizes, int n_in,
                              void* d_out, int out_size, void* d_ws, size_t ws_size,
                              hipStream_t stream) {
    const float* x      = (const float*)d_in[0];
    const float* qk_w   = (const float*)d_in[1];
    const float* qk_b   = (const float*)d_in[2];
    const float* wq_w   = (const float*)d_in[3];
    const float* wq_b   = (const float*)d_in[4];
    const float* wk_w   = (const float*)d_in[5];
    const float* wk_b   = (const float*)d_in[6];
    const float* fch_w  = (const float*)d_in[7];
    const float* fch_b  = (const float*)d_in[8];
    const float* conv_w = (const float*)d_in[9];
    const float* conv_b = (const float*)d_in[10];
    float* out = (float*)d_out;
    float* attn_out = out + (size_t)B_ * COUT_ * DWH;   // tuple part 2
    float* ws = (float*)d_ws;

    k_pool<<<B_ * C_, 256, 0, stream>>>(x, ws + OFF_XMEAN);
    k_combine<<<226, 128, 0, stream>>>(qk_w, qk_b, wq_w, wq_b, wk_w, wk_b,
                                       fch_b, conv_w, conv_b,
                                       ws + OFF_WQT, ws + OFF_WKT,
                                       ws + OFF_BQ, ws + OFF_BK, ws + OFF_BETA);
    k_qkh<<<dim3(C_, B_), 512, 0, stream>>>(ws + OFF_XMEAN, ws + OFF_WQT, ws + OFF_WKT,
                                            ws + OFF_BQ, ws + OFF_BK,
                                            ws + OFF_QH, ws + OFF_KH);
    k_attn<<<dim3(32, B_), 256, 0, stream>>>(ws + OFF_QH, ws + OFF_KH, fch_w, fch_b,
                                             ws + OFF_A, attn_out);
    k_M<<<dim3(32, B_), 256, 0, stream>>>(ws + OFF_A, conv_w, ws + OFF_M);
    k_out<<<dim3(216, B_), 256, 0, stream>>>(ws + OFF_M, x, ws + OFF_BETA, out);
}

// Round 2
// 166.283 us; speedup vs baseline: 1.7205x; 1.7205x over previous
//
#include <hip/hip_runtime.h>
#include <cstdint>
#include <cstddef>

#define B_    8
#define C_    256
#define DWH   13824      // 24*24*24
#define P3    27
#define JW    512        // HEADS*WORD
#define COUT_ 256

// ---- workspace layout (float offsets) ----
#define OFF_XMEAN 0               // B*C*27          = 55296
#define OFF_WQT   55296           // 27*512 (transposed) = 13824
#define OFF_WKT   69120           // 13824
#define OFF_BQ    82944           // 512
#define OFF_BK    83456           // 512
#define OFF_BETA  83968           // 256
#define OFF_QH    84224           // B*C*512 = 1048576
#define OFF_KH    1132800         // 1048576
#define OFF_A     2181376         // B*C*C = 524288
#define OFF_MHI   2705664         // B*256*256 ushort = 262144 floats
#define OFF_MLO   2967808         // 262144 floats
// total = 3229952 floats = 12.92 MB (same footprint as round-0)

typedef __attribute__((ext_vector_type(8))) short bf16x8;   // 8 bf16 = 4 VGPR
typedef __attribute__((ext_vector_type(4))) float f32x4;

__device__ __forceinline__ void split_bf16(float v, unsigned short& h, unsigned short& l) {
    unsigned u  = __float_as_uint(v);
    unsigned hu = u & 0xFFFF0000u;
    float r = v - __uint_as_float(hu);          // exact residual
    h = (unsigned short)(u >> 16);
    l = (unsigned short)(__float_as_uint(r) >> 16);
}

// ============ K1: 3x3x3 block-mean pool ============
__global__ __launch_bounds__(256) void k_pool(const float* __restrict__ x,
                                              float* __restrict__ xmean) {
    int bc = blockIdx.x;
    __shared__ float p0[576], p1[576], p2[576];
    const float* xb = x + (size_t)bc * DWH;
    for (int t = threadIdx.x; t < 576; t += 256) {
        int g  = t >> 6;
        int s  = t & 63;
        int pd = g / 3, pw = g % 3;
        int d  = pd * 8 + (s >> 3);
        int w  = pw * 8 + (s & 7);
        const float4* r = (const float4*)(xb + ((size_t)d * 24 + w) * 24);
        float4 f0 = r[0], f1 = r[1], f2 = r[2], f3 = r[3], f4v = r[4], f5 = r[5];
        p0[t] = f0.x + f0.y + f0.z + f0.w + f1.x + f1.y + f1.z + f1.w;
        p1[t] = f2.x + f2.y + f2.z + f2.w + f3.x + f3.y + f3.z + f3.w;
        p2[t] = f4v.x + f4v.y + f4v.z + f4v.w + f5.x + f5.y + f5.z + f5.w;
    }
    __syncthreads();
    int tid = threadIdx.x;
    if (tid < 27) {
        int pd = tid / 9, pw = (tid / 3) % 3, ph = tid % 3;
        int g = pd * 3 + pw;
        const float* src = (ph == 0) ? p0 : (ph == 1 ? p1 : p2);
        float s = 0.f;
        #pragma unroll 8
        for (int i = 0; i < 64; ++i) s += src[g * 64 + i];
        xmean[(size_t)bc * P3 + tid] = s * (1.0f / 512.0f);
    }
}

// ============ K2: fold projection chains ============
__global__ __launch_bounds__(128) void k_combine(
    const float* __restrict__ qk_w, const float* __restrict__ qk_b,
    const float* __restrict__ wq_w, const float* __restrict__ wq_b,
    const float* __restrict__ wk_w, const float* __restrict__ wk_b,
    const float* __restrict__ fch_b, const float* __restrict__ conv_w,
    const float* __restrict__ conv_b,
    float* __restrict__ WqT, float* __restrict__ WkT,
    float* __restrict__ bq, float* __restrict__ bk, float* __restrict__ beta) {
    int t = blockIdx.x * 128 + threadIdx.x;
    if (t < 13824) {
        int j = t / 27, p = t % 27;
        float s = 0.f;
        for (int e = 0; e < 128; ++e) s += wq_w[j * 128 + e] * qk_w[e * 27 + p];
        WqT[p * 512 + j] = s;
    } else if (t < 27648) {
        int u = t - 13824, j = u / 27, p = u % 27;
        float s = 0.f;
        for (int e = 0; e < 128; ++e) s += wk_w[j * 128 + e] * qk_w[(128 + e) * 27 + p];
        WkT[p * 512 + j] = s;
    } else if (t < 28160) {
        int j = t - 27648;
        float s = wq_b[j];
        for (int e = 0; e < 128; ++e) s += wq_w[j * 128 + e] * qk_b[e];
        bq[j] = s;
    } else if (t < 28672) {
        int j = t - 28160;
        float s = wk_b[j];
        for (int e = 0; e < 128; ++e) s += wk_w[j * 128 + e] * qk_b[128 + e];
        bk[j] = s;
    } else if (t < 28928) {
        int o = t - 28672;
        float s = 0.f;
        for (int c = 0; c < 256; ++c) s += conv_w[o * 256 + c];
        beta[o] = fch_b[0] * s + conv_b[o];
    }
}

// ============ K3: qh/kh projections ============
__global__ __launch_bounds__(512) void k_qkh(
    const float* __restrict__ xmean, const float* __restrict__ WqT,
    const float* __restrict__ WkT, const float* __restrict__ bq,
    const float* __restrict__ bk, float* __restrict__ qh, float* __restrict__ kh) {
    int bc = blockIdx.y * C_ + blockIdx.x;
    __shared__ float xm[P3];
    if (threadIdx.x < P3) xm[threadIdx.x] = xmean[(size_t)bc * P3 + threadIdx.x];
    __syncthreads();
    int j = threadIdx.x;
    float q = bq[j], k = bk[j];
    #pragma unroll
    for (int p = 0; p < P3; ++p) {
        float xv = xm[p];
        q += WqT[p * 512 + j] * xv;
        k += WkT[p * 512 + j] * xv;
    }
    qh[(size_t)bc * JW + j] = q * 0.125f;
    kh[(size_t)bc * JW + j] = k;
}

// ============ K4: scores + softmax + head-combine -> A, attn_out ============
__global__ __launch_bounds__(256) void k_attn(
    const float* __restrict__ qh, const float* __restrict__ kh,
    const float* __restrict__ fch_w, const float* __restrict__ fch_b,
    float* __restrict__ A, float* __restrict__ attn_out) {
    int b = blockIdx.y;
    int c0 = blockIdx.x * 8;
    int t = threadIdx.x;
    __shared__ float qs[8 * JW];
    __shared__ float ss[8][256];
    __shared__ float mx[8], den[8];
    {
        const float4* src = (const float4*)(qh + ((size_t)(b * C_ + c0)) * JW);
        float4* dst = (float4*)qs;
        #pragma unroll
        for (int i = 0; i < 4; ++i) dst[t + 256 * i] = src[t + 256 * i];
    }
    float areg[8];
    #pragma unroll
    for (int i = 0; i < 8; ++i) areg[i] = 0.f;
    __syncthreads();
    int lane = t & 63, wv = t >> 6;
    for (int h = 0; h < 8; ++h) {
        float khv[64];
        const float4* kp = (const float4*)(kh + ((size_t)(b * C_ + t)) * JW + h * 64);
        #pragma unroll
        for (int i = 0; i < 16; ++i) {
            float4 v = kp[i];
            khv[i * 4] = v.x; khv[i * 4 + 1] = v.y; khv[i * 4 + 2] = v.z; khv[i * 4 + 3] = v.w;
        }
        #pragma unroll
        for (int cl = 0; cl < 8; ++cl) {
            const float4* qrow = (const float4*)(qs + cl * JW + h * 64);
            float dot = 0.f;
            #pragma unroll
            for (int i = 0; i < 16; ++i) {
                float4 qv = qrow[i];
                dot += qv.x * khv[i * 4] + qv.y * khv[i * 4 + 1]
                     + qv.z * khv[i * 4 + 2] + qv.w * khv[i * 4 + 3];
            }
            ss[cl][t] = dot;
        }
        __syncthreads();
        #pragma unroll
        for (int rr = 0; rr < 2; ++rr) {
            int cl = wv * 2 + rr;
            float4 v = *(const float4*)&ss[cl][lane * 4];
            float m = fmaxf(fmaxf(v.x, v.y), fmaxf(v.z, v.w));
            for (int off = 32; off; off >>= 1) m = fmaxf(m, __shfl_xor(m, off, 64));
            float s = expf(v.x - m) + expf(v.y - m) + expf(v.z - m) + expf(v.w - m);
            for (int off = 32; off; off >>= 1) s += __shfl_xor(s, off, 64);
            if (lane == 0) { mx[cl] = m; den[cl] = s; }
        }
        __syncthreads();
        float fw = fch_w[h];
        #pragma unroll
        for (int cl = 0; cl < 8; ++cl)
            areg[cl] += expf(ss[cl][t] - mx[cl]) * (fw / den[cl]);
        __syncthreads();
    }
    float fb = fch_b[0];
    #pragma unroll
    for (int cl = 0; cl < 8; ++cl) {
        size_t idx = ((size_t)(b * C_ + c0 + cl)) * C_ + t;
        A[idx] = areg[cl];
        attn_out[idx] = areg[cl] + fb;
    }
}

// ============ K5: M[b] = conv_w @ A[b] + conv_w, emitted as bf16 hi/lo ============
__global__ __launch_bounds__(256) void k_M(
    const float* __restrict__ A, const float* __restrict__ conv_w,
    unsigned short* __restrict__ Mhi, unsigned short* __restrict__ Mlo) {
    int b = blockIdx.y;
    int o0 = blockIdx.x * 8;
    int t = threadIdx.x;
    __shared__ float cw[8][256];
    #pragma unroll
    for (int r = 0; r < 8; ++r) cw[r][t] = conv_w[(o0 + r) * 256 + t];
    __syncthreads();
    float acc[8] = {0.f, 0.f, 0.f, 0.f, 0.f, 0.f, 0.f, 0.f};
    const float* Ab = A + (size_t)b * C_ * C_;
    for (int c = 0; c < 256; ++c) {
        float av = Ab[(size_t)c * 256 + t];
        #pragma unroll
        for (int r = 0; r < 8; ++r) acc[r] += cw[r][c] * av;
    }
    #pragma unroll
    for (int r = 0; r < 8; ++r) {
        float mv = acc[r] + conv_w[(o0 + r) * 256 + t];
        unsigned short h, l;
        split_bf16(mv, h, l);
        size_t idx = ((size_t)(b * C_) + o0 + r) * 256 + t;
        Mhi[idx] = h;
        Mlo[idx] = l;
    }
}

// ============ K6: out[b,o,n] = sum_k M[b,o,k]*x[b,k,n] + beta[o]  (bf16-split MFMA) ====
// block: 256 thr = 4 waves; tile 256(o) x 64(n); BK=32; wave w owns o in [64w,64w+64)
// LDS tiles XOR-swizzled at 16B-slot granularity: byte ^= ((row&3)<<4)  (row stride 64B)
__global__ __launch_bounds__(256, 2) void k_out_mfma(
    const unsigned short* __restrict__ Mhi, const unsigned short* __restrict__ Mlo,
    const float* __restrict__ x, const float* __restrict__ beta,
    float* __restrict__ out) {
    int b  = blockIdx.y;
    int n0 = blockIdx.x * 64;
    int t  = threadIdx.x;
    int lane = t & 63, wv = t >> 6;
    int wo   = wv * 64;
    int l15  = lane & 15;
    int kseg = lane >> 4;            // 0..3 -> k = kseg*8 + i
    int kbyte = kseg * 16;           // byte col of the 8 contiguous bf16

    __shared__ __align__(16) unsigned short MsH[256 * 32];   // [o][k] swizzled, 16 KB
    __shared__ __align__(16) unsigned short MsL[256 * 32];
    __shared__ __align__(16) unsigned short XsH[64 * 32];    // [n][k] swizzled, 4 KB
    __shared__ __align__(16) unsigned short XsL[64 * 32];

    f32x4 acc[4][4];
    #pragma unroll
    for (int m = 0; m < 4; ++m)
        #pragma unroll
        for (int nf = 0; nf < 4; ++nf) acc[m][nf] = (f32x4){0.f, 0.f, 0.f, 0.f};

    const float* xb = x + (size_t)b * 256 * DWH;
    const unsigned short* gh = Mhi + (size_t)b * 256 * 256;
    const unsigned short* gl = Mlo + (size_t)b * 256 * 256;

    for (int k0 = 0; k0 < 256; k0 += 32) {
        if (k0) __syncthreads();
        // ---- stage M[0:256][k0:k0+32] hi/lo ----
        {
            int c4   = t & 3;                 // 16B chunk in 64B row
            int orow = t >> 2;                // 0..63
            #pragma unroll
            for (int it = 0; it < 4; ++it) {
                int o = it * 64 + orow;
                size_t gidx = (size_t)o * 256 + k0 + c4 * 8;
                uint4 vh = *(const uint4*)(gh + gidx);
                uint4 vl = *(const uint4*)(gl + gidx);
                int off = o * 64 + ((c4 * 16) ^ ((o & 3) << 4));
                *(uint4*)((char*)MsH + off) = vh;
                *(uint4*)((char*)MsL + off) = vl;
            }
        }
        // ---- stage x[k0:k0+32][n0:n0+64] -> Xs[n][k] hi/lo (transposed, converted) ----
        {
            int n     = t & 63;
            int khalf = t >> 6;               // 0..3, covers k = khalf*8 + j
            const float* xcol = xb + (size_t)(k0 + khalf * 8) * DWH + n0 + n;
            unsigned h[8], l[8];
            #pragma unroll
            for (int j = 0; j < 8; ++j) {
                float v = xcol[(size_t)j * DWH];
                unsigned short hh, ll;
                split_bf16(v, hh, ll);
                h[j] = hh; l[j] = ll;
            }
            uint4 vh, vl;
            vh.x = h[0] | (h[1] << 16); vh.y = h[2] | (h[3] << 16);
            vh.z = h[4] | (h[5] << 16); vh.w = h[6] | (h[7] << 16);
            vl.x = l[0] | (l[1] << 16); vl.y = l[2] | (l[3] << 16);
            vl.z = l[4] | (l[5] << 16); vl.w = l[6] | (l[7] << 16);
            int off = n * 64 + ((khalf * 16) ^ ((n & 3) << 4));
            *(uint4*)((char*)XsH + off) = vh;
            *(uint4*)((char*)XsL + off) = vl;
        }
        __syncthreads();
        // ---- fragments + MFMA ----
        bf16x8 Ah[4], Al[4], Bh[4], Bl[4];
        #pragma unroll
        for (int m = 0; m < 4; ++m) {
            int o = wo + m * 16 + l15;
            int off = o * 64 + (kbyte ^ ((o & 3) << 4));
            Ah[m] = *(const bf16x8*)((const char*)MsH + off);
            Al[m] = *(const bf16x8*)((const char*)MsL + off);
        }
        #pragma unroll
        for (int nf = 0; nf < 4; ++nf) {
            int n = nf * 16 + l15;
            int off = n * 64 + (kbyte ^ ((n & 3) << 4));
            Bh[nf] = *(const bf16x8*)((const char*)XsH + off);
            Bl[nf] = *(const bf16x8*)((const char*)XsL + off);
        }
        #pragma unroll
        for (int m = 0; m < 4; ++m)
            #pragma unroll
            for (int nf = 0; nf < 4; ++nf) {
                f32x4 c = acc[m][nf];
                c = __builtin_amdgcn_mfma_f32_16x16x32_bf16(Al[m], Bh[nf], c, 0, 0, 0);
                c = __builtin_amdgcn_mfma_f32_16x16x32_bf16(Ah[m], Bl[nf], c, 0, 0, 0);
                c = __builtin_amdgcn_mfma_f32_16x16x32_bf16(Ah[m], Bh[nf], c, 0, 0, 0);
                acc[m][nf] = c;
            }
    }

    // ---- epilogue: D layout col=lane&15, row=(lane>>4)*4+reg ----
    int r4 = (lane >> 4) * 4;
    #pragma unroll
    for (int m = 0; m < 4; ++m) {
        int obase = wo + m * 16 + r4;
        float bet[4];
        #pragma unroll
        for (int r = 0; r < 4; ++r) bet[r] = beta[obase + r];
        #pragma unroll
        for (int nf = 0; nf < 4; ++nf) {
            int n = n0 + nf * 16 + l15;
            #pragma unroll
            for (int r = 0; r < 4; ++r)
                out[((size_t)(b * 256 + obase + r)) * DWH + n] = acc[m][nf][r] + bet[r];
        }
    }
}

extern "C" void kernel_launch(void* const* d_in, const int* in_sizes, int n_in,
                              void* d_out, int out_size, void* d_ws, size_t ws_size,
                              hipStream_t stream) {
    const float* x      = (const float*)d_in[0];
    const float* qk_w   = (const float*)d_in[1];
    const float* qk_b   = (const float*)d_in[2];
    const float* wq_w   = (const float*)d_in[3];
    const float* wq_b   = (const float*)d_in[4];
    const float* wk_w   = (const float*)d_in[5];
    const float* wk_b   = (const float*)d_in[6];
    const float* fch_w  = (const float*)d_in[7];
    const float* fch_b  = (const float*)d_in[8];
    const float* conv_w = (const float*)d_in[9];
    const float* conv_b = (const float*)d_in[10];
    float* out = (float*)d_out;
    float* attn_out = out + (size_t)B_ * COUT_ * DWH;
    float* ws = (float*)d_ws;
    unsigned short* Mhi = (unsigned short*)(ws + OFF_MHI);
    unsigned short* Mlo = (unsigned short*)(ws + OFF_MLO);

    k_pool<<<B_ * C_, 256, 0, stream>>>(x, ws + OFF_XMEAN);
    k_combine<<<226, 128, 0, stream>>>(qk_w, qk_b, wq_w, wq_b, wk_w, wk_b,
                                       fch_b, conv_w, conv_b,
                                       ws + OFF_WQT, ws + OFF_WKT,
                                       ws + OFF_BQ, ws + OFF_BK, ws + OFF_BETA);
    k_qkh<<<dim3(C_, B_), 512, 0, stream>>>(ws + OFF_XMEAN, ws + OFF_WQT, ws + OFF_WKT,
                                            ws + OFF_BQ, ws + OFF_BK,
                                            ws + OFF_QH, ws + OFF_KH);
    k_attn<<<dim3(32, B_), 256, 0, stream>>>(ws + OFF_QH, ws + OFF_KH, fch_w, fch_b,
                                             ws + OFF_A, attn_out);
    k_M<<<dim3(32, B_), 256, 0, stream>>>(ws + OFF_A, conv_w, Mhi, Mlo);
    k_out_mfma<<<dim3(216, B_), 256, 0, stream>>>(Mhi, Mlo, x, ws + OFF_BETA, out);
}

// Round 3
// 144.997 us; speedup vs baseline: 1.9731x; 1.1468x over previous
//
#include <hip/hip_runtime.h>
#include <cstdint>
#include <cstddef>

#define B_    8
#define C_    256
#define DWH   13824      // 24*24*24
#define P3    27
#define COUT_ 256

// ---- workspace layout (float offsets) ----
#define OFF_XMEAN 0               // B*C*27 = 55296
#define OFF_WQT   55296           // 27*512 = 13824
#define OFF_WKT   69120           // 13824
#define OFF_BQ    82944           // 512
#define OFF_BK    83456           // 512
#define OFF_BETA  83968           // 256
#define OFF_G     84224           // 8*27*28 (padded) = 6048
#define OFF_U     90272           // 8*27 = 216
#define OFF_V     90488           // 216
#define OFF_D     90704           // 8
#define OFF_ZT    90712           // B*8*7*256*4 = 458752 (z~ transposed, float4 granules)
#define OFF_A     549464          // B*256*256 = 524288
#define OFF_MHI   1073752         // B*256*256 ushort = 262144 floats
#define OFF_MLO   1335896         // 262144
// total = 1598040 floats = 6.4 MB

typedef __attribute__((ext_vector_type(8))) short bf16x8;
typedef __attribute__((ext_vector_type(4))) float f32x4;

__device__ __forceinline__ void split_bf16(float v, unsigned short& h, unsigned short& l) {
    unsigned u  = __float_as_uint(v);
    unsigned hu = u & 0xFFFF0000u;
    float r = v - __uint_as_float(hu);
    h = (unsigned short)(u >> 16);
    l = (unsigned short)(__float_as_uint(r) >> 16);
}

// ============ K1: 3x3x3 block-mean pool ============
__global__ __launch_bounds__(256) void k_pool(const float* __restrict__ x,
                                              float* __restrict__ xmean) {
    int bc = blockIdx.x;
    __shared__ float p0[576], p1[576], p2[576];
    const float* xb = x + (size_t)bc * DWH;
    for (int t = threadIdx.x; t < 576; t += 256) {
        int g  = t >> 6;
        int s  = t & 63;
        int pd = g / 3, pw = g % 3;
        int d  = pd * 8 + (s >> 3);
        int w  = pw * 8 + (s & 7);
        const float4* r = (const float4*)(xb + ((size_t)d * 24 + w) * 24);
        float4 f0 = r[0], f1 = r[1], f2 = r[2], f3 = r[3], f4v = r[4], f5 = r[5];
        p0[t] = f0.x + f0.y + f0.z + f0.w + f1.x + f1.y + f1.z + f1.w;
        p1[t] = f2.x + f2.y + f2.z + f2.w + f3.x + f3.y + f3.z + f3.w;
        p2[t] = f4v.x + f4v.y + f4v.z + f4v.w + f5.x + f5.y + f5.z + f5.w;
    }
    __syncthreads();
    int tid = threadIdx.x;
    if (tid < 27) {
        int pd = tid / 9, pw = (tid / 3) % 3, ph = tid % 3;
        int g = pd * 3 + pw;
        const float* src = (ph == 0) ? p0 : (ph == 1 ? p1 : p2);
        float s = 0.f;
        #pragma unroll 8
        for (int i = 0; i < 64; ++i) s += src[g * 64 + i];
        xmean[(size_t)bc * P3 + tid] = s * (1.0f / 512.0f);
    }
}

// ============ K2: fold projection chains ============
__global__ __launch_bounds__(128) void k_combine(
    const float* __restrict__ qk_w, const float* __restrict__ qk_b,
    const float* __restrict__ wq_w, const float* __restrict__ wq_b,
    const float* __restrict__ wk_w, const float* __restrict__ wk_b,
    const float* __restrict__ fch_b, const float* __restrict__ conv_w,
    const float* __restrict__ conv_b,
    float* __restrict__ WqT, float* __restrict__ WkT,
    float* __restrict__ bq, float* __restrict__ bk, float* __restrict__ beta) {
    int t = blockIdx.x * 128 + threadIdx.x;
    if (t < 13824) {
        int j = t / 27, p = t % 27;
        float s = 0.f;
        for (int e = 0; e < 128; ++e) s += wq_w[j * 128 + e] * qk_w[e * 27 + p];
        WqT[p * 512 + j] = s;
    } else if (t < 27648) {
        int u = t - 13824, j = u / 27, p = u % 27;
        float s = 0.f;
        for (int e = 0; e < 128; ++e) s += wk_w[j * 128 + e] * qk_w[(128 + e) * 27 + p];
        WkT[p * 512 + j] = s;
    } else if (t < 28160) {
        int j = t - 27648;
        float s = wq_b[j];
        for (int e = 0; e < 128; ++e) s += wq_w[j * 128 + e] * qk_b[e];
        bq[j] = s;
    } else if (t < 28672) {
        int j = t - 28160;
        float s = wk_b[j];
        for (int e = 0; e < 128; ++e) s += wk_w[j * 128 + e] * qk_b[128 + e];
        bk[j] = s;
    } else if (t < 28928) {
        int o = t - 28672;
        float s = 0.f;
        for (int c = 0; c < 256; ++c) s += conv_w[o * 256 + c];
        beta[o] = fch_b[0] * s + conv_b[o];
    }
}

// ============ K2b: per-head bilinear forms  G_h = 0.125*WqT_h^T WkT_h  (+u,v,d) ====
// G stored padded [h][27][28] (pad col = 0)
__global__ __launch_bounds__(256) void k_G(
    const float* __restrict__ WqT, const float* __restrict__ WkT,
    const float* __restrict__ bq, const float* __restrict__ bk,
    float* __restrict__ G, float* __restrict__ U,
    float* __restrict__ V, float* __restrict__ D) {
    int h = blockIdx.x;
    int base = h * 64;
    for (int idx = threadIdx.x; idx < 811; idx += 256) {
        if (idx < 756) {
            int p = idx / 28, r = idx % 28;
            float s = 0.f;
            if (r < 27)
                for (int w = 0; w < 64; ++w)
                    s += WqT[p * 512 + base + w] * WkT[r * 512 + base + w];
            G[(h * 27 + p) * 28 + r] = 0.125f * s;
        } else if (idx < 783) {
            int p = idx - 756;                 // V[p] multiplies xm[c][p]
            float s = 0.f;
            for (int w = 0; w < 64; ++w) s += WqT[p * 512 + base + w] * bk[base + w];
            V[h * 27 + p] = 0.125f * s;
        } else if (idx < 810) {
            int r = idx - 783;                 // U[r] multiplies xm[k][r]
            float s = 0.f;
            for (int w = 0; w < 64; ++w) s += WkT[r * 512 + base + w] * bq[base + w];
            U[h * 27 + r] = 0.125f * s;
        } else {
            float s = 0.f;
            for (int w = 0; w < 64; ++w) s += bq[base + w] * bk[base + w];
            D[h] = 0.125f * s;
        }
    }
}

// ============ K2c: z~[b,h,k][28] = [G_h xm[k] + v_h ; u_h.xm[k] + d_h], transposed store
// ZT layout (float4 units): ZT4[((b*8+h)*7 + p4)*256 + k]
__global__ __launch_bounds__(256) void k_z(
    const float* __restrict__ xmean, const float* __restrict__ G,
    const float* __restrict__ U, const float* __restrict__ V,
    const float* __restrict__ D, float* __restrict__ ZT) {
    int h = blockIdx.x, b = blockIdx.y;
    int k = threadIdx.x;
    __shared__ float Gs[756], Us[27], Vs[27], Ds;
    for (int idx = threadIdx.x; idx < 756; idx += 256) Gs[idx] = G[h * 756 + idx];
    if (threadIdx.x < 27) { Us[threadIdx.x] = U[h * 27 + threadIdx.x];
                            Vs[threadIdx.x] = V[h * 27 + threadIdx.x]; }
    if (threadIdx.x == 27) Ds = D[h];
    __syncthreads();
    float xm[28];
    const float* xp = xmean + ((size_t)(b * C_) + k) * P3;
    #pragma unroll
    for (int r = 0; r < 27; ++r) xm[r] = xp[r];
    xm[27] = 0.f;
    float z[28];
    #pragma unroll
    for (int p = 0; p < 27; ++p) {
        float acc = Vs[p];
        #pragma unroll
        for (int r4 = 0; r4 < 7; ++r4) {
            float4 g = *(const float4*)&Gs[p * 28 + r4 * 4];
            acc += g.x * xm[r4 * 4] + g.y * xm[r4 * 4 + 1]
                 + g.z * xm[r4 * 4 + 2] + g.w * xm[r4 * 4 + 3];
        }
        z[p] = acc;
    }
    {
        float e = Ds;
        #pragma unroll
        for (int r = 0; r < 27; ++r) e += Us[r] * xm[r];
        z[27] = e;
    }
    float4* zt = (float4*)ZT;
    int bh = b * 8 + h;
    #pragma unroll
    for (int p4 = 0; p4 < 7; ++p4) {
        float4 v = {z[p4 * 4], z[p4 * 4 + 1], z[p4 * 4 + 2], z[p4 * 4 + 3]};
        zt[((size_t)(bh * 7 + p4)) * 256 + k] = v;
    }
}

// ============ K4: scores (rank-28 dot) + softmax + head-combine -> A, attn_out ========
// block = (b, ctile of 4 rows); thread t = key index; 512 blocks total
__global__ __launch_bounds__(256) void k_attn(
    const float* __restrict__ xmean, const float* __restrict__ ZT,
    const float* __restrict__ fch_w, const float* __restrict__ fch_b,
    float* __restrict__ A, float* __restrict__ attn_out) {
    int b = blockIdx.y;
    int c0 = blockIdx.x * 4;
    int t = threadIdx.x;
    int lane = t & 63, wv = t >> 6;
    __shared__ float xsh[4 * 28];
    __shared__ float ss[4][256];
    __shared__ float mx[4], den[4];
    if (t < 112) {
        int i = t / 28, p = t % 28;
        xsh[t] = (p < 27) ? xmean[((size_t)(b * C_) + c0 + i) * P3 + p] : 1.0f;
    }
    __syncthreads();
    float4 xr[4][7];
    #pragma unroll
    for (int cl = 0; cl < 4; ++cl)
        #pragma unroll
        for (int p4 = 0; p4 < 7; ++p4)
            xr[cl][p4] = *(const float4*)&xsh[cl * 28 + p4 * 4];
    float areg[4] = {0.f, 0.f, 0.f, 0.f};
    const float4* zt = (const float4*)ZT;
    for (int h = 0; h < 8; ++h) {
        int bh = b * 8 + h;
        float4 zk[7];
        #pragma unroll
        for (int p4 = 0; p4 < 7; ++p4)
            zk[p4] = zt[((size_t)(bh * 7 + p4)) * 256 + t];
        #pragma unroll
        for (int cl = 0; cl < 4; ++cl) {
            float dot = 0.f;
            #pragma unroll
            for (int p4 = 0; p4 < 7; ++p4) {
                float4 xv = xr[cl][p4];
                float4 zv = zk[p4];
                dot += xv.x * zv.x + xv.y * zv.y + xv.z * zv.z + xv.w * zv.w;
            }
            ss[cl][t] = dot;
        }
        __syncthreads();
        {
            int cl = wv;                       // 4 waves, one row each
            float4 v = *(const float4*)&ss[cl][lane * 4];
            float m = fmaxf(fmaxf(v.x, v.y), fmaxf(v.z, v.w));
            for (int off = 32; off; off >>= 1) m = fmaxf(m, __shfl_xor(m, off, 64));
            float s = expf(v.x - m) + expf(v.y - m) + expf(v.z - m) + expf(v.w - m);
            for (int off = 32; off; off >>= 1) s += __shfl_xor(s, off, 64);
            if (lane == 0) { mx[cl] = m; den[cl] = s; }
        }
        __syncthreads();
        float fw = fch_w[h];
        #pragma unroll
        for (int cl = 0; cl < 4; ++cl)
            areg[cl] += expf(ss[cl][t] - mx[cl]) * (fw / den[cl]);
        __syncthreads();
    }
    float fb = fch_b[0];
    #pragma unroll
    for (int cl = 0; cl < 4; ++cl) {
        size_t idx = ((size_t)(b * C_) + c0 + cl) * C_ + t;
        A[idx] = areg[cl];
        attn_out[idx] = areg[cl] + fb;
    }
}

// ============ K5: M[b] = conv_w @ A[b] + conv_w, bf16 hi/lo ============
__global__ __launch_bounds__(256) void k_M(
    const float* __restrict__ A, const float* __restrict__ conv_w,
    unsigned short* __restrict__ Mhi, unsigned short* __restrict__ Mlo) {
    int b = blockIdx.y;
    int o0 = blockIdx.x * 8;
    int t = threadIdx.x;
    __shared__ float cw[8][256];
    #pragma unroll
    for (int r = 0; r < 8; ++r) cw[r][t] = conv_w[(o0 + r) * 256 + t];
    __syncthreads();
    float acc[8] = {0.f, 0.f, 0.f, 0.f, 0.f, 0.f, 0.f, 0.f};
    const float* Ab = A + (size_t)b * C_ * C_;
    for (int c = 0; c < 256; ++c) {
        float av = Ab[(size_t)c * 256 + t];
        #pragma unroll
        for (int r = 0; r < 8; ++r) acc[r] += cw[r][c] * av;
    }
    #pragma unroll
    for (int r = 0; r < 8; ++r) {
        float mv = acc[r] + conv_w[(o0 + r) * 256 + t];
        unsigned short h, l;
        split_bf16(mv, h, l);
        size_t idx = ((size_t)(b * C_) + o0 + r) * 256 + t;
        Mhi[idx] = h;
        Mlo[idx] = l;
    }
}

// ============ K6: out = M@x + beta  (bf16-split MFMA) — unchanged from round 2 ====
__global__ __launch_bounds__(256, 2) void k_out_mfma(
    const unsigned short* __restrict__ Mhi, const unsigned short* __restrict__ Mlo,
    const float* __restrict__ x, const float* __restrict__ beta,
    float* __restrict__ out) {
    int b  = blockIdx.y;
    int n0 = blockIdx.x * 64;
    int t  = threadIdx.x;
    int lane = t & 63, wv = t >> 6;
    int wo   = wv * 64;
    int l15  = lane & 15;
    int kseg = lane >> 4;
    int kbyte = kseg * 16;

    __shared__ __align__(16) unsigned short MsH[256 * 32];
    __shared__ __align__(16) unsigned short MsL[256 * 32];
    __shared__ __align__(16) unsigned short XsH[64 * 32];
    __shared__ __align__(16) unsigned short XsL[64 * 32];

    f32x4 acc[4][4];
    #pragma unroll
    for (int m = 0; m < 4; ++m)
        #pragma unroll
        for (int nf = 0; nf < 4; ++nf) acc[m][nf] = (f32x4){0.f, 0.f, 0.f, 0.f};

    const float* xb = x + (size_t)b * 256 * DWH;
    const unsigned short* gh = Mhi + (size_t)b * 256 * 256;
    const unsigned short* gl = Mlo + (size_t)b * 256 * 256;

    for (int k0 = 0; k0 < 256; k0 += 32) {
        if (k0) __syncthreads();
        {
            int c4   = t & 3;
            int orow = t >> 2;
            #pragma unroll
            for (int it = 0; it < 4; ++it) {
                int o = it * 64 + orow;
                size_t gidx = (size_t)o * 256 + k0 + c4 * 8;
                uint4 vh = *(const uint4*)(gh + gidx);
                uint4 vl = *(const uint4*)(gl + gidx);
                int off = o * 64 + ((c4 * 16) ^ ((o & 3) << 4));
                *(uint4*)((char*)MsH + off) = vh;
                *(uint4*)((char*)MsL + off) = vl;
            }
        }
        {
            int n     = t & 63;
            int khalf = t >> 6;
            const float* xcol = xb + (size_t)(k0 + khalf * 8) * DWH + n0 + n;
            unsigned h[8], l[8];
            #pragma unroll
            for (int j = 0; j < 8; ++j) {
                float v = xcol[(size_t)j * DWH];
                unsigned short hh, ll;
                split_bf16(v, hh, ll);
                h[j] = hh; l[j] = ll;
            }
            uint4 vh, vl;
            vh.x = h[0] | (h[1] << 16); vh.y = h[2] | (h[3] << 16);
            vh.z = h[4] | (h[5] << 16); vh.w = h[6] | (h[7] << 16);
            vl.x = l[0] | (l[1] << 16); vl.y = l[2] | (l[3] << 16);
            vl.z = l[4] | (l[5] << 16); vl.w = l[6] | (l[7] << 16);
            int off = n * 64 + ((khalf * 16) ^ ((n & 3) << 4));
            *(uint4*)((char*)XsH + off) = vh;
            *(uint4*)((char*)XsL + off) = vl;
        }
        __syncthreads();
        bf16x8 Ah[4], Al[4], Bh[4], Bl[4];
        #pragma unroll
        for (int m = 0; m < 4; ++m) {
            int o = wo + m * 16 + l15;
            int off = o * 64 + (kbyte ^ ((o & 3) << 4));
            Ah[m] = *(const bf16x8*)((const char*)MsH + off);
            Al[m] = *(const bf16x8*)((const char*)MsL + off);
        }
        #pragma unroll
        for (int nf = 0; nf < 4; ++nf) {
            int n = nf * 16 + l15;
            int off = n * 64 + (kbyte ^ ((n & 3) << 4));
            Bh[nf] = *(const bf16x8*)((const char*)XsH + off);
            Bl[nf] = *(const bf16x8*)((const char*)XsL + off);
        }
        #pragma unroll
        for (int m = 0; m < 4; ++m)
            #pragma unroll
            for (int nf = 0; nf < 4; ++nf) {
                f32x4 c = acc[m][nf];
                c = __builtin_amdgcn_mfma_f32_16x16x32_bf16(Al[m], Bh[nf], c, 0, 0, 0);
                c = __builtin_amdgcn_mfma_f32_16x16x32_bf16(Ah[m], Bl[nf], c, 0, 0, 0);
                c = __builtin_amdgcn_mfma_f32_16x16x32_bf16(Ah[m], Bh[nf], c, 0, 0, 0);
                acc[m][nf] = c;
            }
    }

    int r4 = (lane >> 4) * 4;
    #pragma unroll
    for (int m = 0; m < 4; ++m) {
        int obase = wo + m * 16 + r4;
        float bet[4];
        #pragma unroll
        for (int r = 0; r < 4; ++r) bet[r] = beta[obase + r];
        #pragma unroll
        for (int nf = 0; nf < 4; ++nf) {
            int n = n0 + nf * 16 + l15;
            #pragma unroll
            for (int r = 0; r < 4; ++r)
                out[((size_t)(b * 256 + obase + r)) * DWH + n] = acc[m][nf][r] + bet[r];
        }
    }
}

extern "C" void kernel_launch(void* const* d_in, const int* in_sizes, int n_in,
                              void* d_out, int out_size, void* d_ws, size_t ws_size,
                              hipStream_t stream) {
    const float* x      = (const float*)d_in[0];
    const float* qk_w   = (const float*)d_in[1];
    const float* qk_b   = (const float*)d_in[2];
    const float* wq_w   = (const float*)d_in[3];
    const float* wq_b   = (const float*)d_in[4];
    const float* wk_w   = (const float*)d_in[5];
    const float* wk_b   = (const float*)d_in[6];
    const float* fch_w  = (const float*)d_in[7];
    const float* fch_b  = (const float*)d_in[8];
    const float* conv_w = (const float*)d_in[9];
    const float* conv_b = (const float*)d_in[10];
    float* out = (float*)d_out;
    float* attn_out = out + (size_t)B_ * COUT_ * DWH;
    float* ws = (float*)d_ws;
    unsigned short* Mhi = (unsigned short*)(ws + OFF_MHI);
    unsigned short* Mlo = (unsigned short*)(ws + OFF_MLO);

    k_pool<<<B_ * C_, 256, 0, stream>>>(x, ws + OFF_XMEAN);
    k_combine<<<226, 128, 0, stream>>>(qk_w, qk_b, wq_w, wq_b, wk_w, wk_b,
                                       fch_b, conv_w, conv_b,
                                       ws + OFF_WQT, ws + OFF_WKT,
                                       ws + OFF_BQ, ws + OFF_BK, ws + OFF_BETA);
    k_G<<<8, 256, 0, stream>>>(ws + OFF_WQT, ws + OFF_WKT, ws + OFF_BQ, ws + OFF_BK,
                               ws + OFF_G, ws + OFF_U, ws + OFF_V, ws + OFF_D);
    k_z<<<dim3(8, B_), 256, 0, stream>>>(ws + OFF_XMEAN, ws + OFF_G, ws + OFF_U,
                                         ws + OFF_V, ws + OFF_D, ws + OFF_ZT);
    k_attn<<<dim3(64, B_), 256, 0, stream>>>(ws + OFF_XMEAN, ws + OFF_ZT, fch_w, fch_b,
                                             ws + OFF_A, attn_out);
    k_M<<<dim3(32, B_), 256, 0, stream>>>(ws + OFF_A, conv_w, Mhi, Mlo);
    k_out_mfma<<<dim3(216, B_), 256, 0, stream>>>(Mhi, Mlo, x, ws + OFF_BETA, out);
}